// Round 20
// baseline (564.545 us; speedup 1.0000x reference)
//
#include <hip/hip_runtime.h>

#define NC 128      // channels
#define NB 8        // batch
#define CPB 32      // channels per block = 8 lanes x float4

__device__ __forceinline__ float4 ld4(const float* p) { return *(const float4*)p; }
__device__ __forceinline__ float4 add4(float4 a, float4 b) {
    return make_float4(a.x + b.x, a.y + b.y, a.z + b.z, a.w + b.w);
}
__device__ __forceinline__ float4 sub4(float4 a, float4 b) {
    return make_float4(a.x - b.x, a.y - b.y, a.z - b.z, a.w - b.w);
}
__device__ __forceinline__ float4 muls4(float4 a, float s) {
    return make_float4(a.x * s, a.y * s, a.z * s, a.w * s);
}
__device__ __forceinline__ float4 fma4(float4 a, float4 w, float4 c) {
    return make_float4(fmaf(a.x, w.x, c.x), fmaf(a.y, w.y, c.y),
                       fmaf(a.z, w.z, c.z), fmaf(a.w, w.w, c.w));
}

// ---------------------------------------------------------------------------
// LL-only Haar downsample: P (NB, 2h, 2w, NC) -> out (NB, h, w, NC)
// ---------------------------------------------------------------------------
__global__ __launch_bounds__(256) void k_haar_ll(
    const float* __restrict__ P, float* __restrict__ out, int h, int w)
{
    int idx = blockIdx.x * blockDim.x + threadIdx.x;
    int total = NB * h * w * (NC / 4);
    if (idx >= total) return;
    int cq = idx & (NC / 4 - 1);
    int t  = idx / (NC / 4);
    int j  = t % w; t /= w;
    int i  = t % h;
    int b  = t / h;
    size_t W2C  = (size_t)(2 * w) * NC;
    size_t base = (((size_t)b * (2 * h) + 2 * i) * (2 * w) + 2 * j) * NC + cq * 4;
    float4 A  = *(const float4*)(P + base);
    float4 Bv = *(const float4*)(P + base + NC);
    float4 Cv = *(const float4*)(P + base + W2C);
    float4 Dv = *(const float4*)(P + base + W2C + NC);
    float4 r;
    r.x = (A.x + Bv.x + Cv.x + Dv.x) * 0.5f;
    r.y = (A.y + Bv.y + Cv.y + Dv.y) * 0.5f;
    r.z = (A.z + Bv.z + Cv.z + Dv.z) * 0.5f;
    r.w = (A.w + Bv.w + Cv.w + Dv.w) * 0.5f;
    *(float4*)(out + (size_t)idx * 4) = r;
}

// ---------------------------------------------------------------------------
// Fused conv-on-haar-subbands + inverse (+ base depthwise for level 0).
// float4 channels (8 lanes x 4ch), masked sliding window (mask-muls kept:
// they are independent VALU work that hides load latency — maskless R8/R15
// stalled). nll prefetched at kernel top (R19, -19us).
// NEW vs R19: the BASE conv is relocated from the main tap loop to the
// per-s epilogue. During the main loop live state is exactly R18's RR=2
// wavelet-only set (124 VGPR, under the 128 cliff); in the epilogue the
// wavelet accs die per-s, freeing space for the base accs. This enables
// RR=2 on level-0: wavelet loads 100->60, ds_reads ~halved per output.
// sched_barrier(0) stops the compiler hoisting base loads into the main
// loop (the VGPR-explosion failure mode). Base re-loads are L1-hot.
// blockDim = (8,32). grid = (ceil(w/(32*RR))*4, h, NB). bx = jtile*4+cg.
// ---------------------------------------------------------------------------
#define WL4(s, t)  (wl + ((s) * 25 + (t)) * CPB + 4 * tc)
#define WB4(m, n)  (wbase + ((m) * 5 + (n)) * CPB + 4 * tc)

template <bool BASE, int RR>
__global__ __launch_bounds__(256) void k_convinv(
    const float* __restrict__ P, const float* __restrict__ nll,
    const float* __restrict__ wk, const float* __restrict__ wsc,
    const float* __restrict__ bk, const float* __restrict__ bb,
    const float* __restrict__ bs, float* __restrict__ out,
    int h, int w)
{
    extern __shared__ float lds[];
    float* wl     = lds;               // [4][25][CPB]
    float* wbase  = wl + 4 * 25 * CPB; // [25][CPB]   (BASE)
    float* bscale = wbase + 25 * CPB;  // [CPB]       (BASE)
    float* bbias  = bscale + CPB;      // [CPB]       (BASE)

    const int cg    = blockIdx.x & 3;
    const int jtile = blockIdx.x >> 2;
    const int c0    = cg * CPB;
    const int tid   = threadIdx.x + threadIdx.y * 8;

    for (int u = tid; u < 4 * 25 * CPB; u += 256) {
        int tcc = u & (CPB - 1);
        int st  = u / CPB;
        int t   = st % 25;
        int s   = st / 25;
        wl[u] = 0.5f * wsc[(c0 + tcc) * 4 + s] * wk[t * (4 * NC) + (c0 + tcc) * 4 + s];
    }
    if (BASE) {
        for (int u = tid; u < 25 * CPB; u += 256) {
            int tcc = u & (CPB - 1);
            int t   = u / CPB;
            wbase[u] = bk[t * NC + c0 + tcc];
        }
        if (tid < CPB) { bscale[tid] = bs[c0 + tid]; bbias[tid] = bb[c0 + tid]; }
    }
    __syncthreads();

    const int tc = threadIdx.x;        // 0..7 (channel-quad lane)
    const int cc = c0 + 4 * tc;        // first channel of this lane's quad
    const int b  = blockIdx.z;
    const int i  = blockIdx.y;
    const int ja = jtile * (32 * RR) + threadIdx.y * RR;  // first output j
    if (ja >= w) return;                                  // after syncthreads
    const int PH = 2 * h;
    const size_t rowC = (size_t)(2 * w) * NC;

    // Prefetch next_ll at kernel top (HBM latency overlaps the conv loop).
    float4 nv[RR];
    #pragma unroll
    for (int s = 0; s < RR; ++s) {
        int j = ja + s;
        nv[s] = (nll && j < w)
              ? ld4(nll + (((size_t)b * h + i) * w + j) * NC + cc)
              : make_float4(0.f, 0.f, 0.f, 0.f);
    }

    // Per-column clamped element offsets + validity masks (col = ja + q - 2).
    int   coff[RR + 4];
    float cmask[RR + 4];
    #pragma unroll
    for (int q = 0; q < RR + 4; ++q) {
        int xq  = ja + q - 2;
        int xqc = min(max(xq, 0), w - 1);
        coff[q]  = xqc * (2 * NC);
        cmask[q] = (xq >= 0 && xq < w) ? 1.f : 0.f;
    }

    float4 acc0[RR], acc1[RR], acc2[RR], acc3[RR];
    #pragma unroll
    for (int s = 0; s < RR; ++s)
        acc0[s] = acc1[s] = acc2[s] = acc3[s] = make_float4(0.f, 0.f, 0.f, 0.f);

    // ---------------------- main loop: wavelet conv only ------------------
    #pragma unroll
    for (int ky = 0; ky < 5; ++ky) {
        int y = i + ky - 2;
        if (y < 0 || y >= h) continue;          // block-uniform branch
        const float* prA = P + ((size_t)b * PH + 2 * y) * rowC + cc;
        const float* prC = prA + rowC;
        #pragma unroll
        for (int q = 0; q < RR + 4; ++q) {
            float m = cmask[q];
            const float* pA = prA + coff[q];
            const float* pC = prC + coff[q];
            float4 A  = muls4(ld4(pA), m);
            float4 Bv = muls4(ld4(pA + NC), m);
            float4 Cv = muls4(ld4(pC), m);
            float4 Dv = muls4(ld4(pC + NC), m);
            float4 sA = add4(A, Bv), sC = add4(Cv, Dv);
            float4 dA = sub4(A, Bv), dC = sub4(Cv, Dv);
            float4 s0 = add4(sA, sC), s1 = sub4(sA, sC);
            float4 s2 = add4(dA, dC), s3 = sub4(dA, dC);
            #pragma unroll
            for (int s = 0; s < RR; ++s) {
                const int kx = q - s;          // tap index for output s
                if (kx < 0 || kx > 4) continue;
                const int t = ky * 5 + kx;
                acc0[s] = fma4(s0, ld4(WL4(0, t)), acc0[s]);
                acc1[s] = fma4(s1, ld4(WL4(1, t)), acc1[s]);
                acc2[s] = fma4(s2, ld4(WL4(2, t)), acc2[s]);
                acc3[s] = fma4(s3, ld4(WL4(3, t)), acc3[s]);
            }
        }
    }

    if (BASE) __builtin_amdgcn_sched_barrier(0);  // keep base loads out of phase A

    // ------------- epilogue: per-s combine (+ base conv if BASE) ----------
    #pragma unroll
    for (int s = 0; s < RR; ++s) {
        int j = ja + s;
        if (j >= w) break;
        float4 a0 = add4(acc0[s], nv[s]);
        float4 av = muls4(add4(add4(a0, acc1[s]), add4(acc2[s], acc3[s])), 0.5f);
        float4 bv = muls4(sub4(add4(a0, acc1[s]), add4(acc2[s], acc3[s])), 0.5f);
        float4 cv = muls4(add4(sub4(a0, acc1[s]), sub4(acc2[s], acc3[s])), 0.5f);
        float4 dv = muls4(sub4(sub4(a0, acc1[s]), sub4(acc2[s], acc3[s])), 0.5f);

        size_t ob = ((size_t)b * PH + 2 * i) * rowC + (size_t)(2 * j) * NC + cc;
        if (BASE) {
            float4 b00 = make_float4(0.f, 0.f, 0.f, 0.f);
            float4 b01 = b00, b10 = b00, b11 = b00;
            #pragma unroll
            for (int ky = 1; ky <= 3; ++ky) {
                int y = i + ky - 2;
                if (y < 0 || y >= h) continue;   // block-uniform
                const float* prA = P + ((size_t)b * PH + 2 * y) * rowC + cc;
                const float* prC = prA + rowC;
                #pragma unroll
                for (int kx = 1; kx <= 3; ++kx) {
                    const int q = s + kx;        // col = j + kx - 2
                    float m = cmask[q];
                    const float* pA = prA + coff[q];
                    const float* pC = prC + coff[q];
                    float4 A  = muls4(ld4(pA), m);
                    float4 Bv = muls4(ld4(pA + NC), m);
                    float4 Cv = muls4(ld4(pC), m);
                    float4 Dv = muls4(ld4(pC + NC), m);
                    b00 = fma4(A, ld4(WB4(2 * ky - 2, 2 * kx - 2)), b00);
                    if (kx >= 2)            b01 = fma4(A,  ld4(WB4(2 * ky - 2, 2 * kx - 3)), b01);
                    if (ky >= 2)            b10 = fma4(A,  ld4(WB4(2 * ky - 3, 2 * kx - 2)), b10);
                    if (ky >= 2 && kx >= 2) b11 = fma4(A,  ld4(WB4(2 * ky - 3, 2 * kx - 3)), b11);
                    if (kx <= 2)            b00 = fma4(Bv, ld4(WB4(2 * ky - 2, 2 * kx - 1)), b00);
                                            b01 = fma4(Bv, ld4(WB4(2 * ky - 2, 2 * kx - 2)), b01);
                    if (ky >= 2 && kx <= 2) b10 = fma4(Bv, ld4(WB4(2 * ky - 3, 2 * kx - 1)), b10);
                    if (ky >= 2)            b11 = fma4(Bv, ld4(WB4(2 * ky - 3, 2 * kx - 2)), b11);
                    if (ky <= 2)            b00 = fma4(Cv, ld4(WB4(2 * ky - 1, 2 * kx - 2)), b00);
                    if (ky <= 2 && kx >= 2) b01 = fma4(Cv, ld4(WB4(2 * ky - 1, 2 * kx - 3)), b01);
                                            b10 = fma4(Cv, ld4(WB4(2 * ky - 2, 2 * kx - 2)), b10);
                    if (kx >= 2)            b11 = fma4(Cv, ld4(WB4(2 * ky - 2, 2 * kx - 3)), b11);
                    if (ky <= 2 && kx <= 2) b00 = fma4(Dv, ld4(WB4(2 * ky - 1, 2 * kx - 1)), b00);
                    if (ky <= 2)            b01 = fma4(Dv, ld4(WB4(2 * ky - 1, 2 * kx - 2)), b01);
                    if (kx <= 2)            b10 = fma4(Dv, ld4(WB4(2 * ky - 2, 2 * kx - 1)), b10);
                                            b11 = fma4(Dv, ld4(WB4(2 * ky - 2, 2 * kx - 2)), b11);
                }
            }
            float4 sc = ld4(bscale + 4 * tc);
            float4 bi = ld4(bbias + 4 * tc);
            float4 o00 = make_float4(sc.x * (b00.x + bi.x), sc.y * (b00.y + bi.y),
                                     sc.z * (b00.z + bi.z), sc.w * (b00.w + bi.w));
            float4 o01 = make_float4(sc.x * (b01.x + bi.x), sc.y * (b01.y + bi.y),
                                     sc.z * (b01.z + bi.z), sc.w * (b01.w + bi.w));
            float4 o10 = make_float4(sc.x * (b10.x + bi.x), sc.y * (b10.y + bi.y),
                                     sc.z * (b10.z + bi.z), sc.w * (b10.w + bi.w));
            float4 o11 = make_float4(sc.x * (b11.x + bi.x), sc.y * (b11.y + bi.y),
                                     sc.z * (b11.z + bi.z), sc.w * (b11.w + bi.w));
            *(float4*)(out + ob)             = add4(o00, av);
            *(float4*)(out + ob + NC)        = add4(o01, bv);
            *(float4*)(out + ob + rowC)      = add4(o10, cv);
            *(float4*)(out + ob + rowC + NC) = add4(o11, dv);
        } else {
            *(float4*)(out + ob)             = av;
            *(float4*)(out + ob + NC)        = bv;
            *(float4*)(out + ob + rowC)      = cv;
            *(float4*)(out + ob + rowC + NC) = dv;
        }
    }
}

// ---------------------------------------------------------------------------
extern "C" void kernel_launch(void* const* d_in, const int* in_sizes, int n_in,
                              void* d_out, int out_size, void* d_ws, size_t ws_size,
                              hipStream_t stream)
{
    const float* x  = (const float*)d_in[0];
    const float* bk = (const float*)d_in[1];
    const float* bb = (const float*)d_in[2];
    const float* bs = (const float*)d_in[3];
    const float* wk[3];
    const float* wv[3];
    if (n_in >= 10) {
        for (int i = 0; i < 3; ++i) {
            wk[i] = (const float*)d_in[4 + i];
            wv[i] = (const float*)d_in[7 + i];
        }
    } else {
        const float* wkc = (const float*)d_in[4];
        const float* wvc = (const float*)d_in[5];
        for (int i = 0; i < 3; ++i) {
            wk[i] = wkc + (size_t)i * 25 * 4 * NC;
            wv[i] = wvc + (size_t)i * 4 * NC;
        }
    }
    float* out = (float*)d_out;

    // Dead-before-final intermediates live inside d_out (fully rewritten by
    // the final kernel). r1 (read during final pass) lives in d_ws.
    float* ll0 = out;                       // (8,128,128,128)
    float* ll1 = out + 16777216;            // (8, 64, 64,128)
    float* r2  = out + 16777216 + 4194304;  // (8, 64, 64,128)
    float* r1  = (float*)d_ws;              // (8,128,128,128) = 64 MiB

    // 1) x -> ll0
    {
        int total = NB * 128 * 128 * (NC / 4);
        k_haar_ll<<<(total + 255) / 256, 256, 0, stream>>>(x, ll0, 128, 128);
    }
    // 2) ll0 -> ll1
    {
        int total = NB * 64 * 64 * (NC / 4);
        k_haar_ll<<<(total + 255) / 256, 256, 0, stream>>>(ll0, ll1, 64, 64);
    }

    size_t lds_nb = (size_t)(4 * 25 * CPB) * sizeof(float);                      // 12800 B
    size_t lds_b  = (size_t)(4 * 25 * CPB + 25 * CPB + 2 * CPB) * sizeof(float); // 16256 B
    dim3 blk(8, 32);

    // 3) level 2: ll1 -> r2   (coeff grid 32x32, RR=1)
    k_convinv<false, 1><<<dim3(4, 32, NB), blk, lds_nb, stream>>>(
        ll1, nullptr, wk[2], wv[2], nullptr, nullptr, nullptr, r2, 32, 32);

    // 4) level 1: ll0 (+r2) -> r1   (coeff grid 64x64, RR=2)
    k_convinv<false, 2><<<dim3(4, 64, NB), blk, lds_nb, stream>>>(
        ll0, r2, wk[1], wv[1], nullptr, nullptr, nullptr, r1, 64, 64);

    // 5) level 0: x (+r1) + base path -> d_out   (RR=2, base in epilogue)
    k_convinv<true, 2><<<dim3(2 * 4, 128, NB), blk, lds_b, stream>>>(
        x, r1, wk[0], wv[0], bk, bb, bs, out, 128, 128);
}

// Round 21
// 557.380 us; speedup vs baseline: 1.0129x; 1.0129x over previous
//
#include <hip/hip_runtime.h>

#define NC 128      // channels
#define NB 8        // batch
#define CPB 32      // channels per block = 8 lanes x float4

__device__ __forceinline__ float4 ld4(const float* p) { return *(const float4*)p; }
__device__ __forceinline__ float4 add4(float4 a, float4 b) {
    return make_float4(a.x + b.x, a.y + b.y, a.z + b.z, a.w + b.w);
}
__device__ __forceinline__ float4 sub4(float4 a, float4 b) {
    return make_float4(a.x - b.x, a.y - b.y, a.z - b.z, a.w - b.w);
}
__device__ __forceinline__ float4 muls4(float4 a, float s) {
    return make_float4(a.x * s, a.y * s, a.z * s, a.w * s);
}
__device__ __forceinline__ float4 fma4(float4 a, float4 w, float4 c) {
    return make_float4(fmaf(a.x, w.x, c.x), fmaf(a.y, w.y, c.y),
                       fmaf(a.z, w.z, c.z), fmaf(a.w, w.w, c.w));
}

// ---------------------------------------------------------------------------
// LL-only Haar downsample: P (NB, 2h, 2w, NC) -> out (NB, h, w, NC)
// ---------------------------------------------------------------------------
__global__ __launch_bounds__(256) void k_haar_ll(
    const float* __restrict__ P, float* __restrict__ out, int h, int w)
{
    int idx = blockIdx.x * blockDim.x + threadIdx.x;
    int total = NB * h * w * (NC / 4);
    if (idx >= total) return;
    int cq = idx & (NC / 4 - 1);
    int t  = idx / (NC / 4);
    int j  = t % w; t /= w;
    int i  = t % h;
    int b  = t / h;
    size_t W2C  = (size_t)(2 * w) * NC;
    size_t base = (((size_t)b * (2 * h) + 2 * i) * (2 * w) + 2 * j) * NC + cq * 4;
    float4 A  = *(const float4*)(P + base);
    float4 Bv = *(const float4*)(P + base + NC);
    float4 Cv = *(const float4*)(P + base + W2C);
    float4 Dv = *(const float4*)(P + base + W2C + NC);
    float4 r;
    r.x = (A.x + Bv.x + Cv.x + Dv.x) * 0.5f;
    r.y = (A.y + Bv.y + Cv.y + Dv.y) * 0.5f;
    r.z = (A.z + Bv.z + Cv.z + Dv.z) * 0.5f;
    r.w = (A.w + Bv.w + Cv.w + Dv.w) * 0.5f;
    *(float4*)(out + (size_t)idx * 4) = r;
}

// ---------------------------------------------------------------------------
// Fused conv-on-haar-subbands + inverse (+ base depthwise for level 0).
// R19 configuration — session best (558us total, level-0 430us):
// float4 channels (8 lanes x 4ch), masked sliding window (mask-muls kept —
// independent VALU work that hides load latency; maskless R8/R15 stalled),
// inline LDS weights, no launch-bounds cap, nll prefetched at kernel top.
// RR outputs/thread: level-2 RR=1, level-1 RR=2, level-0 RR=1 (base fused
// in-loop; RR=2-with-epilogue-base hit 132 VGPR / 11% occupancy in R20).
// blockDim = (8,32). grid = (ceil(w/(32*RR))*4, h, NB). bx = jtile*4+cg.
// ---------------------------------------------------------------------------
#define WL4(s, t)  (wl + ((s) * 25 + (t)) * CPB + 4 * tc)
#define WB4(m, n)  (wbase + ((m) * 5 + (n)) * CPB + 4 * tc)

template <bool BASE, int RR>
__global__ __launch_bounds__(256) void k_convinv(
    const float* __restrict__ P, const float* __restrict__ nll,
    const float* __restrict__ wk, const float* __restrict__ wsc,
    const float* __restrict__ bk, const float* __restrict__ bb,
    const float* __restrict__ bs, float* __restrict__ out,
    int h, int w)
{
    extern __shared__ float lds[];
    float* wl     = lds;               // [4][25][CPB]
    float* wbase  = wl + 4 * 25 * CPB; // [25][CPB]   (BASE)
    float* bscale = wbase + 25 * CPB;  // [CPB]       (BASE)
    float* bbias  = bscale + CPB;      // [CPB]       (BASE)

    const int cg    = blockIdx.x & 3;
    const int jtile = blockIdx.x >> 2;
    const int c0    = cg * CPB;
    const int tid   = threadIdx.x + threadIdx.y * 8;

    for (int u = tid; u < 4 * 25 * CPB; u += 256) {
        int tcc = u & (CPB - 1);
        int st  = u / CPB;
        int t   = st % 25;
        int s   = st / 25;
        wl[u] = 0.5f * wsc[(c0 + tcc) * 4 + s] * wk[t * (4 * NC) + (c0 + tcc) * 4 + s];
    }
    if (BASE) {
        for (int u = tid; u < 25 * CPB; u += 256) {
            int tcc = u & (CPB - 1);
            int t   = u / CPB;
            wbase[u] = bk[t * NC + c0 + tcc];
        }
        if (tid < CPB) { bscale[tid] = bs[c0 + tid]; bbias[tid] = bb[c0 + tid]; }
    }
    __syncthreads();

    const int tc = threadIdx.x;        // 0..7 (channel-quad lane)
    const int cc = c0 + 4 * tc;        // first channel of this lane's quad
    const int b  = blockIdx.z;
    const int i  = blockIdx.y;
    const int ja = jtile * (32 * RR) + threadIdx.y * RR;  // first output j
    if (ja >= w) return;                                  // after syncthreads
    const int PH = 2 * h;
    const size_t rowC = (size_t)(2 * w) * NC;

    // Prefetch next_ll at kernel top: its HBM latency overlaps the conv loop
    // instead of serializing in the epilogue.
    float4 nv[RR];
    #pragma unroll
    for (int s = 0; s < RR; ++s) {
        int j = ja + s;
        nv[s] = (nll && j < w)
              ? ld4(nll + (((size_t)b * h + i) * w + j) * NC + cc)
              : make_float4(0.f, 0.f, 0.f, 0.f);
    }

    // Per-column clamped element offsets + validity masks (col = ja + q - 2).
    int   coff[RR + 4];
    float cmask[RR + 4];
    #pragma unroll
    for (int q = 0; q < RR + 4; ++q) {
        int xq  = ja + q - 2;
        int xqc = min(max(xq, 0), w - 1);
        coff[q]  = xqc * (2 * NC);
        cmask[q] = (xq >= 0 && xq < w) ? 1.f : 0.f;
    }

    float4 acc0[RR], acc1[RR], acc2[RR], acc3[RR];
    float4 b00[RR], b01[RR], b10[RR], b11[RR];
    #pragma unroll
    for (int s = 0; s < RR; ++s) {
        acc0[s] = acc1[s] = acc2[s] = acc3[s] = make_float4(0.f, 0.f, 0.f, 0.f);
        b00[s] = b01[s] = b10[s] = b11[s] = make_float4(0.f, 0.f, 0.f, 0.f);
    }

    #pragma unroll
    for (int ky = 0; ky < 5; ++ky) {
        int y = i + ky - 2;
        if (y < 0 || y >= h) continue;          // block-uniform branch
        const float* prA = P + ((size_t)b * PH + 2 * y) * rowC + cc;
        const float* prC = prA + rowC;
        #pragma unroll
        for (int q = 0; q < RR + 4; ++q) {
            float m = cmask[q];
            const float* pA = prA + coff[q];
            const float* pC = prC + coff[q];
            float4 A  = muls4(ld4(pA), m);
            float4 Bv = muls4(ld4(pA + NC), m);
            float4 Cv = muls4(ld4(pC), m);
            float4 Dv = muls4(ld4(pC + NC), m);
            float4 sA = add4(A, Bv), sC = add4(Cv, Dv);
            float4 dA = sub4(A, Bv), dC = sub4(Cv, Dv);
            float4 s0 = add4(sA, sC), s1 = sub4(sA, sC);
            float4 s2 = add4(dA, dC), s3 = sub4(dA, dC);
            #pragma unroll
            for (int s = 0; s < RR; ++s) {
                const int kx = q - s;          // tap index for output s
                if (kx < 0 || kx > 4) continue;
                const int t = ky * 5 + kx;
                acc0[s] = fma4(s0, ld4(WL4(0, t)), acc0[s]);
                acc1[s] = fma4(s1, ld4(WL4(1, t)), acc1[s]);
                acc2[s] = fma4(s2, ld4(WL4(2, t)), acc2[s]);
                acc3[s] = fma4(s3, ld4(WL4(3, t)), acc3[s]);
                if (BASE && ky >= 1 && ky <= 3 && kx >= 1 && kx <= 3) {
                    b00[s] = fma4(A, ld4(WB4(2 * ky - 2, 2 * kx - 2)), b00[s]);
                    if (kx >= 2)            b01[s] = fma4(A,  ld4(WB4(2 * ky - 2, 2 * kx - 3)), b01[s]);
                    if (ky >= 2)            b10[s] = fma4(A,  ld4(WB4(2 * ky - 3, 2 * kx - 2)), b10[s]);
                    if (ky >= 2 && kx >= 2) b11[s] = fma4(A,  ld4(WB4(2 * ky - 3, 2 * kx - 3)), b11[s]);
                    if (kx <= 2)            b00[s] = fma4(Bv, ld4(WB4(2 * ky - 2, 2 * kx - 1)), b00[s]);
                                            b01[s] = fma4(Bv, ld4(WB4(2 * ky - 2, 2 * kx - 2)), b01[s]);
                    if (ky >= 2 && kx <= 2) b10[s] = fma4(Bv, ld4(WB4(2 * ky - 3, 2 * kx - 1)), b10[s]);
                    if (ky >= 2)            b11[s] = fma4(Bv, ld4(WB4(2 * ky - 3, 2 * kx - 2)), b11[s]);
                    if (ky <= 2)            b00[s] = fma4(Cv, ld4(WB4(2 * ky - 1, 2 * kx - 2)), b00[s]);
                    if (ky <= 2 && kx >= 2) b01[s] = fma4(Cv, ld4(WB4(2 * ky - 1, 2 * kx - 3)), b01[s]);
                                            b10[s] = fma4(Cv, ld4(WB4(2 * ky - 2, 2 * kx - 2)), b10[s]);
                    if (kx >= 2)            b11[s] = fma4(Cv, ld4(WB4(2 * ky - 2, 2 * kx - 3)), b11[s]);
                    if (ky <= 2 && kx <= 2) b00[s] = fma4(Dv, ld4(WB4(2 * ky - 1, 2 * kx - 1)), b00[s]);
                    if (ky <= 2)            b01[s] = fma4(Dv, ld4(WB4(2 * ky - 1, 2 * kx - 2)), b01[s]);
                    if (kx <= 2)            b10[s] = fma4(Dv, ld4(WB4(2 * ky - 2, 2 * kx - 1)), b10[s]);
                                            b11[s] = fma4(Dv, ld4(WB4(2 * ky - 2, 2 * kx - 2)), b11[s]);
                }
            }
        }
    }

    // ------------------------------ epilogue ------------------------------
    #pragma unroll
    for (int s = 0; s < RR; ++s) {
        int j = ja + s;
        if (j >= w) break;
        float4 a0 = add4(acc0[s], nv[s]);
        float4 av = muls4(add4(add4(a0, acc1[s]), add4(acc2[s], acc3[s])), 0.5f);
        float4 bv = muls4(sub4(add4(a0, acc1[s]), add4(acc2[s], acc3[s])), 0.5f);
        float4 cv = muls4(add4(sub4(a0, acc1[s]), sub4(acc2[s], acc3[s])), 0.5f);
        float4 dv = muls4(sub4(sub4(a0, acc1[s]), sub4(acc2[s], acc3[s])), 0.5f);

        size_t ob = ((size_t)b * PH + 2 * i) * rowC + (size_t)(2 * j) * NC + cc;
        if (BASE) {
            float4 sc = ld4(bscale + 4 * tc);
            float4 bi = ld4(bbias + 4 * tc);
            float4 o00 = make_float4(sc.x * (b00[s].x + bi.x), sc.y * (b00[s].y + bi.y),
                                     sc.z * (b00[s].z + bi.z), sc.w * (b00[s].w + bi.w));
            float4 o01 = make_float4(sc.x * (b01[s].x + bi.x), sc.y * (b01[s].y + bi.y),
                                     sc.z * (b01[s].z + bi.z), sc.w * (b01[s].w + bi.w));
            float4 o10 = make_float4(sc.x * (b10[s].x + bi.x), sc.y * (b10[s].y + bi.y),
                                     sc.z * (b10[s].z + bi.z), sc.w * (b10[s].w + bi.w));
            float4 o11 = make_float4(sc.x * (b11[s].x + bi.x), sc.y * (b11[s].y + bi.y),
                                     sc.z * (b11[s].z + bi.z), sc.w * (b11[s].w + bi.w));
            *(float4*)(out + ob)             = add4(o00, av);
            *(float4*)(out + ob + NC)        = add4(o01, bv);
            *(float4*)(out + ob + rowC)      = add4(o10, cv);
            *(float4*)(out + ob + rowC + NC) = add4(o11, dv);
        } else {
            *(float4*)(out + ob)             = av;
            *(float4*)(out + ob + NC)        = bv;
            *(float4*)(out + ob + rowC)      = cv;
            *(float4*)(out + ob + rowC + NC) = dv;
        }
    }
}

// ---------------------------------------------------------------------------
extern "C" void kernel_launch(void* const* d_in, const int* in_sizes, int n_in,
                              void* d_out, int out_size, void* d_ws, size_t ws_size,
                              hipStream_t stream)
{
    const float* x  = (const float*)d_in[0];
    const float* bk = (const float*)d_in[1];
    const float* bb = (const float*)d_in[2];
    const float* bs = (const float*)d_in[3];
    const float* wk[3];
    const float* wv[3];
    if (n_in >= 10) {
        for (int i = 0; i < 3; ++i) {
            wk[i] = (const float*)d_in[4 + i];
            wv[i] = (const float*)d_in[7 + i];
        }
    } else {
        const float* wkc = (const float*)d_in[4];
        const float* wvc = (const float*)d_in[5];
        for (int i = 0; i < 3; ++i) {
            wk[i] = wkc + (size_t)i * 25 * 4 * NC;
            wv[i] = wvc + (size_t)i * 4 * NC;
        }
    }
    float* out = (float*)d_out;

    // Dead-before-final intermediates live inside d_out (fully rewritten by
    // the final kernel). r1 (read during final pass) lives in d_ws.
    float* ll0 = out;                       // (8,128,128,128)
    float* ll1 = out + 16777216;            // (8, 64, 64,128)
    float* r2  = out + 16777216 + 4194304;  // (8, 64, 64,128)
    float* r1  = (float*)d_ws;              // (8,128,128,128) = 64 MiB

    // 1) x -> ll0
    {
        int total = NB * 128 * 128 * (NC / 4);
        k_haar_ll<<<(total + 255) / 256, 256, 0, stream>>>(x, ll0, 128, 128);
    }
    // 2) ll0 -> ll1
    {
        int total = NB * 64 * 64 * (NC / 4);
        k_haar_ll<<<(total + 255) / 256, 256, 0, stream>>>(ll0, ll1, 64, 64);
    }

    size_t lds_nb = (size_t)(4 * 25 * CPB) * sizeof(float);                      // 12800 B
    size_t lds_b  = (size_t)(4 * 25 * CPB + 25 * CPB + 2 * CPB) * sizeof(float); // 16256 B
    dim3 blk(8, 32);

    // 3) level 2: ll1 -> r2   (coeff grid 32x32, RR=1)
    k_convinv<false, 1><<<dim3(4, 32, NB), blk, lds_nb, stream>>>(
        ll1, nullptr, wk[2], wv[2], nullptr, nullptr, nullptr, r2, 32, 32);

    // 4) level 1: ll0 (+r2) -> r1   (coeff grid 64x64, RR=2)
    k_convinv<false, 2><<<dim3(4, 64, NB), blk, lds_nb, stream>>>(
        ll0, r2, wk[1], wv[1], nullptr, nullptr, nullptr, r1, 64, 64);

    // 5) level 0: x (+r1) + base path -> d_out   (RR=1, R16/R14 config)
    k_convinv<true, 1><<<dim3(4 * 4, 128, NB), blk, lds_b, stream>>>(
        x, r1, wk[0], wv[0], bk, bb, bs, out, 128, 128);
}